// Round 13
// baseline (4467.921 us; speedup 1.0000x reference)
//
#include <hip/hip_runtime.h>
#include <math.h>

namespace {
constexpr int B_ = 128;
constexpr int T_ = 256;
constexpr int D_ = 512;
constexpr int U_ = 1024;
constexpr int N3U = 3 * U_;        // 3072
constexpr int K_TOT = D_ + U_;     // 1536
constexpr int WROWS = 48;          // 3 gates x 16 u
constexpr int ROWB = 3088;         // LDS row stride bytes: (1536+8)*2
constexpr int LDS_BYTES = WROWS * ROWB;   // 148224
constexpr unsigned SENT = 0x7FC07FC0u;    // bf16 NaN pair; unreachable (|h*dec|<=1)
constexpr int POLL_LIM = 1 << 16;
}

#define E_CONST 2.71828182845904523536f

using bf16x8 = __attribute__((ext_vector_type(8))) short;
using f32x4  = __attribute__((ext_vector_type(4))) float;
using u32x4  = __attribute__((ext_vector_type(4))) unsigned int;

__device__ inline unsigned short f2bf(float f) {
    union { float f; unsigned int u; } a; a.f = f;
    unsigned int u = a.u;
    return (unsigned short)((u + 0x7FFFu + ((u >> 16) & 1u)) >> 16);  // RNE
}

__device__ inline bf16x8 cvt8(const float* src) {
    float v[8];
    *reinterpret_cast<float4*>(&v[0]) = *reinterpret_cast<const float4*>(src);
    *reinterpret_cast<float4*>(&v[4]) = *reinterpret_cast<const float4*>(src + 4);
    bf16x8 r;
    #pragma unroll
    for (int j = 0; j < 8; ++j) r[j] = (short)f2bf(v[j]);
    return r;
}

// 16 coherent (L1/L2-bypass, L3-served) 16B loads at base + j*64 bytes.
#define ISSUE16(arr, base)                                                     \
    {                                                                          \
        _Pragma("unroll")                                                      \
        for (int j = 0; j < 16; ++j) {                                         \
            asm volatile("global_load_dwordx4 %0, %1, off offset:%2 sc0 sc1"   \
                         : "=&v"(arr[j])                                       \
                         : "v"(base), "i"(j * 64));                            \
        }                                                                      \
    }
#define PIN16(arr)                                                             \
    {                                                                          \
        _Pragma("unroll")                                                      \
        for (int j = 0; j < 16; ++j) asm volatile("" : "+v"(arr[j]));          \
    }
#define WAITV0 asm volatile("s_waitcnt vmcnt(0)" ::: "memory")

#define SENT_ANY(arr, un)                                                      \
    {                                                                          \
        un = 0;                                                                \
        _Pragma("unroll")                                                      \
        for (int j = 0; j < 16; ++j) {                                         \
            const u32x4 d = __builtin_bit_cast(u32x4, arr[j]);                 \
            un |= (d[0] == SENT) | (d[1] == SENT) |                            \
                  (d[2] == SENT) | (d[3] == SENT);                             \
        }                                                                      \
    }

#define GATHER_RETRY(arr, base)                                                \
    {                                                                          \
        int guard_ = 0;                                                        \
        for (;;) {                                                             \
            ISSUE16(arr, base)                                                 \
            WAITV0; PIN16(arr)                                                 \
            int un_;                                                           \
            SENT_ANY(arr, un_)                                                 \
            if (!__any(un_)) break;                                            \
            if (++guard_ > POLL_LIM) break;   /* safety: no hang */            \
            asm volatile("s_sleep 1");                                         \
        }                                                                      \
    }

// ---- one-time prep: WcatT[n][k] = bf16( k<512 ? Wk[k][n] : Wr[k-512][n] ) ----
__global__ void wprep(const float* __restrict__ Wk, const float* __restrict__ Wr,
                      unsigned short* __restrict__ WcatT) {
    __shared__ unsigned short S[32][33];
    const int kb = blockIdx.x * 32;
    const int nb = blockIdx.y * 32;
    const int tx = threadIdx.x;
    const int ty = threadIdx.y;
    #pragma unroll
    for (int j = 0; j < 4; ++j) {
        const int r = ty + 8 * j;
        const int k = kb + r;
        const int n = nb + tx;
        const float v = (k < D_) ? Wk[(size_t)k * N3U + n]
                                 : Wr[(size_t)(k - D_) * N3U + n];
        S[tx][r] = f2bf(v);
    }
    __syncthreads();
    #pragma unroll
    for (int j = 0; j < 4; ++j) {
        const int r = ty + 8 * j;
        WcatT[(size_t)(nb + r) * K_TOT + kb + tx] = S[r][tx];
    }
}

// ---- one-time prep: decays + poison all 3 h buffers (every replay) ----
__global__ void dprep(const float* __restrict__ dts, float* __restrict__ decays,
                      unsigned int* __restrict__ bufs /* 3*64K dwords */) {
    const int i = blockIdx.x * 256 + threadIdx.x;
    if (i < B_ * T_) decays[i] = 1.0f / logf(E_CONST + dts[i]);
    for (int j = i; j < 3 * B_ * U_ / 2; j += 256 * 384) bufs[j] = SENT;
}

// ---- persistent kernel: autonomous waves, sentinel-data-poll, no barriers ----
// 256 blocks (XCD-clustered), 128 thr = 2 waves. Wave (bg, bt) owns rows
// [bg*32+bt*16, +16) x u-tile [ub*16, +16): x-GEMM + gather-poll h(t) (K=1024,
// two overlapped halves) + 3-gate GEMM + in-wave epilogue + poison + publish.
// Publish = __hip_atomic_store AGENT (merging, L3-resident: 70 MB proven, R9).
__global__ __launch_bounds__(128) void tgru_auto(
    const float* __restrict__ seq,            // [B,T,D] fp32
    const float* __restrict__ decays,         // [B,T]
    const unsigned short* __restrict__ WcatT, // [3072][1536] bf16
    const float* __restrict__ ib,             // [3U]
    const float* __restrict__ rb,             // [3U]
    unsigned short* hb0, unsigned short* hb1, unsigned short* hb2,
    float* __restrict__ out)                  // [B,U]
{
    extern __shared__ char lds[];

    const int tid  = threadIdx.x;
    const int lane = tid & 63;
    const int bt   = tid >> 6;     // 0..1 (wave = bt-half)
    const int l15  = lane & 15;
    const int lk   = lane >> 4;
    const int bid  = blockIdx.x;
    const int bg   = (bid >> 1) & 3;                 // XCD-clustered group
    const int ub   = ((bid >> 3) << 1) | (bid & 1);  // 0..63
    const int u0   = ub * 16;
    const int u    = u0 + l15;
    const int b_base = bg * 32 + bt * 16;

    // ---- stage weights: 48 rows x 1536 k into LDS, once ----
    for (int idx = tid; idx < WROWS * 192; idx += 128) {
        const int c = idx / 192;
        const int o = idx % 192;
        const unsigned short* src =
            WcatT + (size_t)((c >> 4) * U_ + u0 + (c & 15)) * K_TOT + o * 8;
        *reinterpret_cast<bf16x8*>(lds + (size_t)c * ROWB + o * 16) =
            *reinterpret_cast<const bf16x8*>(src);
    }
    __syncthreads();   // the only barrier in the kernel

    const char* wz = lds + (size_t)(0  + l15) * ROWB + 16 * lk;
    const char* wr = lds + (size_t)(16 + l15) * ROWB + 16 * lk;
    const char* wh = lds + (size_t)(32 + l15) * ROWB + 16 * lk;

    unsigned short* bufs[3] = {hb0, hb1, hb2};

    const float bzs  = ib[u] + rb[u];
    const float brs  = ib[U_ + u] + rb[U_ + u];
    const float ibh_ = ib[2 * U_ + u];
    const float rbh_ = rb[2 * U_ + u];

    float hreg[4] = {0.f, 0.f, 0.f, 0.f};   // fp32 h*dec, own (row, u)

    #pragma unroll 1
    for (int t = 0; t < T_; ++t) {
        const unsigned short* gbuf = bufs[t % 3];        // h(t)
        unsigned short*       pbuf = bufs[(t + 1) % 3];  // publish h(t+1)
        unsigned short*       obuf = bufs[(t + 2) % 3];  // poison target

        f32x4 az  = {0.f,0.f,0.f,0.f}, ar  = {0.f,0.f,0.f,0.f};
        f32x4 ahx = {0.f,0.f,0.f,0.f}, ahr = {0.f,0.f,0.f,0.f};
        float decn[4];

        // ---- x-GEMM (K 0..512), 3 gates; fills time before h(t) arrives ----
        {
            const float* ap = seq + ((size_t)(b_base + l15) * T_ + t) * D_ + 8 * lk;
            #pragma unroll 4
            for (int j = 0; j < 16; ++j) {
                const bf16x8 a = cvt8(ap + 32 * j);
                az  = __builtin_amdgcn_mfma_f32_16x16x32_bf16(
                    a, *reinterpret_cast<const bf16x8*>(wz + 64 * j), az, 0, 0, 0);
                ar  = __builtin_amdgcn_mfma_f32_16x16x32_bf16(
                    a, *reinterpret_cast<const bf16x8*>(wr + 64 * j), ar, 0, 0, 0);
                ahx = __builtin_amdgcn_mfma_f32_16x16x32_bf16(
                    a, *reinterpret_cast<const bf16x8*>(wh + 64 * j), ahx, 0, 0, 0);
            }
            const int tn = (t < T_ - 1) ? t + 1 : t;
            #pragma unroll
            for (int q = 0; q < 4; ++q)
                decn[q] = decays[(b_base + 4 * lk + q) * T_ + tn];
        }

        if (t > 0) {
            // ---- gather-poll h(t): rows b_base..+16, K=1024 in 2 halves ----
            const char* hbase =
                (const char*)(gbuf + (size_t)(b_base + l15) * U_ + 8 * lk);
            bf16x8 hv1[16], hv2[16];
            GATHER_RETRY(hv1, hbase)
            ISSUE16(hv2, hbase + 1024)   // half 2 in flight under GEMM1
            #pragma unroll 4
            for (int j = 0; j < 16; ++j) {
                const int o = 1024 + 64 * j;
                az  = __builtin_amdgcn_mfma_f32_16x16x32_bf16(
                    hv1[j], *reinterpret_cast<const bf16x8*>(wz + o), az, 0, 0, 0);
                ar  = __builtin_amdgcn_mfma_f32_16x16x32_bf16(
                    hv1[j], *reinterpret_cast<const bf16x8*>(wr + o), ar, 0, 0, 0);
                ahr = __builtin_amdgcn_mfma_f32_16x16x32_bf16(
                    hv1[j], *reinterpret_cast<const bf16x8*>(wh + o), ahr, 0, 0, 0);
            }
            WAITV0; PIN16(hv2)
            {
                int un_;
                SENT_ANY(hv2, un_)
                if (__any(un_)) { GATHER_RETRY(hv2, hbase + 1024) }
            }
            #pragma unroll 4
            for (int j = 0; j < 16; ++j) {
                const int o = 2048 + 64 * j;
                az  = __builtin_amdgcn_mfma_f32_16x16x32_bf16(
                    hv2[j], *reinterpret_cast<const bf16x8*>(wz + o), az, 0, 0, 0);
                ar  = __builtin_amdgcn_mfma_f32_16x16x32_bf16(
                    hv2[j], *reinterpret_cast<const bf16x8*>(wr + o), ar, 0, 0, 0);
                ahr = __builtin_amdgcn_mfma_f32_16x16x32_bf16(
                    hv2[j], *reinterpret_cast<const bf16x8*>(wh + o), ahr, 0, 0, 0);
            }
        }

        // ---- poison own tile of obuf (safe: gather(t) done => all siblings
        // finished step t-1 => no one still reads obuf's old contents) ----
        if (t < T_ - 2 && (lane & 1) == 0) {
            #pragma unroll
            for (int q = 0; q < 4; ++q) {
                unsigned int* pa = (unsigned int*)(obuf
                    + (size_t)(b_base + 4 * lk + q) * U_ + u);
                __hip_atomic_store(pa, SENT, __ATOMIC_RELAXED,
                                   __HIP_MEMORY_SCOPE_AGENT);
            }
        }

        // ---- in-wave epilogue ----
        float hn[4];
        #pragma unroll
        for (int q = 0; q < 4; ++q) {
            const float z  = 1.0f / (1.0f + expf(-(az[q] + bzs)));
            const float r  = 1.0f / (1.0f + expf(-(ar[q] + brs)));
            const float hh = tanhf(ahx[q] + ibh_ + r * (ahr[q] + rbh_));
            hn[q] = z * hreg[q] + (1.0f - z) * hh;
        }
        if (t == T_ - 1) {
            #pragma unroll
            for (int q = 0; q < 4; ++q)
                out[(size_t)(b_base + 4 * lk + q) * U_ + u] = hn[q];
        } else {
            unsigned int pk[4];
            #pragma unroll
            for (int q = 0; q < 4; ++q) {
                const float hd = hn[q] * decn[q];
                hreg[q] = hd;
                const float po = __shfl_xor(hd, 1);   // partner u (odd lane)
                pk[q] = (unsigned int)f2bf(hd) | ((unsigned int)f2bf(po) << 16);
            }
            WAITV0;   // poison ordered before publish (same addresses at t+1)
            if ((lane & 1) == 0) {
                #pragma unroll
                for (int q = 0; q < 4; ++q) {
                    unsigned int* pa = (unsigned int*)(pbuf
                        + (size_t)(b_base + 4 * lk + q) * U_ + u);
                    __hip_atomic_store(pa, pk[q], __ATOMIC_RELAXED,
                                       __HIP_MEMORY_SCOPE_AGENT);
                }
            }
            // no ack, no flag: the data itself is the signal.
        }
    }
}

extern "C" void kernel_launch(void* const* d_in, const int* in_sizes, int n_in,
                              void* d_out, int out_size, void* d_ws, size_t ws_size,
                              hipStream_t stream) {
    const float* seq = (const float*)d_in[0];
    const float* dts = (const float*)d_in[1];
    const float* Wk  = (const float*)d_in[2];
    const float* Wr  = (const float*)d_in[3];
    const float* ib  = (const float*)d_in[4];
    const float* rb  = (const float*)d_in[5];
    float* out = (float*)d_out;

    char* wsb = (char*)d_ws;
    // ws layout (bytes):
    //   [0,        9437184)   WcatT bf16 [3072][1536]
    //   [9437184,  9568256)   decays fp32 [128][256]
    //   [9568256,  9830400)   hb0 bf16 [128][1024]
    //   [9830400, 10092544)   hb1
    //   [10092544,10354688)   hb2
    unsigned short* wcat   = (unsigned short*)(wsb);
    float*          decays = (float*)(wsb + 9437184);
    unsigned short* hb0    = (unsigned short*)(wsb + 9568256);
    unsigned short* hb1    = (unsigned short*)(wsb + 9830400);
    unsigned short* hb2    = (unsigned short*)(wsb + 10092544);

    wprep<<<dim3(K_TOT / 32, N3U / 32), dim3(32, 8), 0, stream>>>(Wk, Wr, wcat);
    // decays + poison all three h buffers (every launch/replay)
    dprep<<<dim3(384), dim3(256), 0, stream>>>(dts, decays, (unsigned int*)hb0);

    hipFuncSetAttribute((const void*)tgru_auto,
                        hipFuncAttributeMaxDynamicSharedMemorySize, LDS_BYTES);

    tgru_auto<<<dim3(256), dim3(128), LDS_BYTES, stream>>>(
        seq, decays, wcat, ib, rb, hb0, hb1, hb2, out);
}